// Round 9
// baseline (174.787 us; speedup 1.0000x reference)
//
#include <hip/hip_runtime.h>
#include <hip/hip_bf16.h>

#define BATCH 32
#define CH 3
#define HH 256
#define WW 256
#define KS 29
#define PAD 14
#define NT_F 1000.0f

typedef __attribute__((ext_vector_type(8))) short short8;
typedef __attribute__((ext_vector_type(4))) float f32x4;
typedef __attribute__((ext_vector_type(16))) float f32x16;

union U4 { short8 s8; uint4 u4; };

__device__ inline unsigned short bf16rne(float f) {
  unsigned u = __float_as_uint(f);
  unsigned r = (u + 0x7FFFu + ((u >> 16) & 1u)) >> 16;
  return (unsigned short)r;
}
__device__ inline unsigned pk_bf16(float a, float b) {
  union { __hip_bfloat162 h2; unsigned u; } cv;
  cv.h2 = __float22bfloat162_rn(make_float2(a, b));
  return cv.u;
}

// ws float layout:
//   (unused)  [1024]          @ 0
//   tcond [32][32]            @ 1024
//   w1n   ushort[3][32][16]   @ 2048
//   w2c   ushort[9][16][32]   @ 2816  (slot s holds och perm(s))
//   (z region dead as of R9 — blur fused away)
//   partial float[8192]       @ 3151872
//
// LESSONS LOG:
// R1: conv1-write bank fix correct but off critical path.
// R3: XCD swizzle cut convloss FETCH 58.5->18.5MB, dur unchanged.
// R5: private arrays need compile-time indexing (ring mod-6 -> scratch).
// R6: convloss occupancy theory falsified (+13% waves, dur worse).
// R7: barrier-removal neutral. Keep wave-private conv1 variant.
// R8: chunked no-spill blur only 44.9->~43: blur register theory DEAD after
//     3 structurally different impls all land 43-45us. Honest convloss
//     profile: VALUBusy 59.4%, MfmaUtil 27.5 -> VALU is the dominant pipe,
//     ~40% slack. Ledger: fill 45 + blur 43 + convloss 44 + reduce 3 = 135.
// R9 (this): DELETE blur kernel. Fuse blur into convloss by per-tile
//     recompute: stage 48x48x3 x-window (reflect), vertical 29-tap
//     (144 col-strips, R8's compile-time-tap chunk pattern), horizontal
//     (240 thr, acc[5]), pack bf16 into the SAME zs4 layout; conv phases
//     R7-exact. Added ~29K VALU cy/SIMD absorbed into the 44K idle.
//     Weight-prep -> own 1-block kernel (dispatch boundary = ordering).
//     LDS 43.3KB (hsw aliases xw) -> 3 blocks/CU.
//
// NOTE (r14): do NOT fold reduce into convloss via threadfence+atomic --
// device-scope fence across 8 non-coherent XCD L2s = 6x regression.

#define PARTIAL_OFF 3151872

// ---------------- weight/tcond prep (1 block; runs before fused) ----------------
__global__ __launch_bounds__(256) void prep_kernel(
    const int* __restrict__ t, const float* __restrict__ W1,
    const float* __restrict__ b1, const float* __restrict__ tw,
    const float* __restrict__ W2, float* __restrict__ ws) {
  int tid = threadIdx.x;
  float* tcond = ws + 1024;
  unsigned short* w1n = (unsigned short*)(ws + 2048);
  unsigned short* w2c = (unsigned short*)(ws + 2816);
  for (int i = tid; i < 1536; i += 256) {          // w1n [mf][och][slot]
    int mf = i >> 9, r = i & 511;
    int och = r >> 4, s = r & 15;
    int tp = mf * 4 + (s >> 2), ci = s & 3;
    w1n[i] = (ci < 3 && tp < 9) ? bf16rne(W1[och * 27 + ci * 9 + tp])
                                : (unsigned short)0;
  }
  for (int i = tid; i < 4608; i += 256) {          // w2c [tap][oc][slot(perm)]
    int tap = i >> 9, r = i & 511;
    int n = r >> 5, s = r & 31;
    int och = (s & 3) + 8 * ((s >> 2) & 3) + 4 * (s >> 4);   // perm(s)
    int dy = tap / 3, dx = tap - dy * 3;
    w2c[i] = (n < 3) ? bf16rne(W2[((n * 32 + och) * 3 + dy) * 3 + dx])
                     : (unsigned short)0;
  }
  for (int i = tid; i < 1024; i += 256) {          // tcond
    int b = i >> 5, o = i & 31;
    tcond[i] = b1[o] + ((float)t[b] * (1.0f / NT_F)) * tw[o];
  }
}

// ---------------- FUSED blur+conv1+ReLU+conv2+MSE ----------------
// grid (16,16,B); block 256 = 4 waves; 16x16 output tile.
// smem regions (bytes):
//   [0,28224)      xw float[3][48][49] (padded)  -- later ALIASED by hsw (27648)
//   [28224,39984)  vs float[3][20][49]
//   [39984,43184)  zs4 ushort[400][4]  (same layout as pre-fusion)
//   [43184,43312)  gkl float[32]
//   [43312,43328)  wsum float[4]
#define XW_OFF 0
#define VS_OFF 28224
#define ZS_OFF 39984
#define GK_OFF 43184
#define WS_OFF 43312
#define SMEM_BYTES 43328

__global__ __launch_bounds__(256, 3) void convloss_kernel(
    const float* __restrict__ x, const int* __restrict__ t,
    const float* __restrict__ sched, const float* __restrict__ ws,
    const float* __restrict__ b2g, float* __restrict__ partial) {
  __shared__ __align__(16) char smem[SMEM_BYTES];
  float* xw = (float*)(smem + XW_OFF);              // xw[ch*2352 + i*49 + c]
  float* vs = (float*)(smem + VS_OFF);              // vs[ch*980 + r*49 + j]
  unsigned short* zs4 = (unsigned short*)(smem + ZS_OFF);
  float* gkl = (float*)(smem + GK_OFF);
  float* wsum = (float*)(smem + WS_OFF);

  const float* tcond = ws + 1024;
  const unsigned short* w1n = (const unsigned short*)(ws + 2048);
  const unsigned short* w2c = (const unsigned short*)(ws + 2816);

  // XCD-aware bijective swizzle (8192 = 8*1024): keeps each XCD's x slice
  // (~3.1MB) resident in its L2 -> window re-reads are L2 hits.
  int flat = (blockIdx.z * 16 + blockIdx.y) * 16 + blockIdx.x;
  int wid = (flat & 7) * 1024 + (flat >> 3);
  int b = wid >> 8;
  int by = (wid >> 4) & 15;
  int bx = wid & 15;

  int tid = threadIdx.x;
  int x0 = bx * 16, y0 = by * 16;

  int lane = tid & 63;
  int q = lane >> 4;        // quad (16x16 shapes)
  int col = lane & 15;      // 16x16 m/n index
  int col32 = lane & 31;    // 32x32 n index (pixel)
  int h = lane >> 5;        // 32x32 half
  int wv = tid >> 6;        // wave id

  int colc = (col < 3) ? col : 0;
  float b2v = b2g[colc];

  const float* xb = x + (size_t)b * 3 * HH * WW;

  // MSE x prefetch issued FIRST (cold HBM stream; consumed at the very end)
  float4 xpre[4];
#pragma unroll
  for (int i = 0; i < 4; i++) {
    int g2 = wv * 4 + i;
    xpre[i] = *(const float4*)&xb[colc * (HH * WW) + (y0 + g2) * WW + x0 + q * 4];
  }

  // ---- stage x window: rows y0-16..y0+31, cols x0-16..x0+31, 3 ch, reflect
  // 3 ch x 9 iters x 256 thr = 6912 loads (48x48 per ch)
#pragma unroll
  for (int ch = 0; ch < 3; ch++) {
#pragma unroll
    for (int kk = 0; kk < 9; kk++) {
      int e2 = tid + 256 * kk;           // 0..2303
      int i = e2 / 48;
      int c = e2 - i * 48;
      int gy = y0 - 16 + i;
      gy = (gy < 0) ? -gy : gy;
      gy = (gy >= HH) ? (2 * HH - 2 - gy) : gy;
      int gx = x0 - 16 + c;
      gx = (gx < 0) ? -gx : gx;
      gx = (gx >= WW) ? (2 * WW - 2 - gx) : gx;
      xw[ch * 2352 + i * 49 + c] = xb[ch * (HH * WW) + gy * WW + gx];
    }
  }

  // wave 0 computes this batch's gaussian kernel
  if (tid < 64) {
    float wexp = 0.0f;
    if (tid < KS) {
      float sigma = sched[t[b]];
      float xg = (float)(tid - PAD) / sigma;
      wexp = expf(-0.5f * xg * xg);
    }
    float s = wexp;
#pragma unroll
    for (int off = 32; off > 0; off >>= 1) s += __shfl_down(s, off);
    float tot = __shfl(s, 0);
    if (tid < 32) gkl[tid] = wexp / tot;
  }
  __syncthreads();   // F1: xw + gkl ready

  float gk[KS];
#pragma unroll
  for (int kk = 0; kk < KS; kk++) gk[kk] = gkl[kk];   // uniform broadcast

  // ---- vertical pass: 144 column-strips (3ch x 48 cols), 2 chunks of 10 rows
  // (R8's proven compile-time-tap pattern; acc[10]+gk[29] ~ 45 live regs)
  if (tid < 144) {
    int ch = tid / 48;
    int c = tid - ch * 48;
    const float* xcol = xw + ch * 2352 + c;
    float* vcol = vs + ch * 980 + c;
#pragma unroll
    for (int c2 = 0; c2 < 2; c2++) {
      float acc[10];
#pragma unroll
      for (int yy = 0; yy < 10; yy++) acc[yy] = 0.0f;
#pragma unroll
      for (int i = 0; i < 38; i++) {
        float v = xcol[(c2 * 10 + i) * 49];
#pragma unroll
        for (int yy = 0; yy < 10; yy++) {
          int kk = i - yy;                 // compile-time per (i,yy)
          if (kk >= 0 && kk < KS) acc[yy] += gk[kk] * v;
        }
      }
#pragma unroll
      for (int yy = 0; yy < 10; yy++) vcol[(c2 * 10 + yy) * 49] = acc[yy];
    }
  }
  __syncthreads();   // F2: vs ready (xw dead -> hsw may alias)

  // ---- horizontal pass: 240 units = 3ch x 20 rows x 4 quarters (5 px each)
  // writes bf16 into zs4 [py*20+px][ci] (identical layout to pre-fusion);
  // SAME zero-pad: out-of-image pixels -> 0; ch2 writes b32 zeroing pad slot.
  if (tid < 240) {
    int ch = tid / 80;
    int rr = tid - ch * 80;
    int row = rr >> 2;
    int qd = rr & 3;
    int px0 = qd * 5;
    const float* vrow = vs + ch * 980 + row * 49;
    float acc[5];
#pragma unroll
    for (int p = 0; p < 5; p++) acc[p] = 0.0f;
#pragma unroll
    for (int j = 0; j < 33; j++) {
      float v = vrow[px0 + j];
#pragma unroll
      for (int p = 0; p < 5; p++) {
        int kk = j - p;                    // compile-time per (j,p)
        if (kk >= 0 && kk < KS) acc[p] += gk[kk] * v;
      }
    }
    int gy = y0 - 2 + row;
    bool rv = ((unsigned)gy < (unsigned)HH);
#pragma unroll
    for (int p = 0; p < 5; p++) {
      int px = px0 + p;
      int gx = x0 - 2 + px;
      float zv = (rv && ((unsigned)gx < (unsigned)WW)) ? acc[p] : 0.0f;
      unsigned short zb = bf16rne(zv);
      int idx = (row * 20 + px) * 4;
      if (ch == 2)
        *(unsigned*)&zs4[idx + 2] = (unsigned)zb;   // slot2 = z, slot3(pad) = 0
      else
        zs4[idx + ch] = zb;
    }
  }
  __syncthreads();   // F3: zs4 ready

  // ---- conv weights/bias fragments (L2-hot; loaded late to cut reg pressure)
  U4 W0, W1f, W2f;
  W0.u4  = *(const uint4*)(w1n + 0 * 512 + col32 * 16 + h * 8);
  W1f.u4 = *(const uint4*)(w1n + 1 * 512 + col32 * 16 + h * 8);
  W2f.u4 = *(const uint4*)(w1n + 2 * 512 + col32 * 16 + h * 8);

  f32x16 tc16;
#pragma unroll
  for (int r1 = 0; r1 < 4; r1++) {
    float4 v = *(const float4*)(tcond + b * 32 + 4 * h + 8 * r1);
    tc16[4 * r1 + 0] = v.x;
    tc16[4 * r1 + 1] = v.y;
    tc16[4 * r1 + 2] = v.z;
    tc16[4 * r1 + 3] = v.w;
  }

  // per-lane b64 read offsets (ushort units) for the 3 MFMAs' tap pairs
  int oA0 = h ? 8 : 0, oB0 = h ? 80 : 4;
  int oA1 = h ? 160 : 84, oB1 = h ? 164 : 88;
  const int oA2 = 168;

  // ---- conv1: wave-private strips (R7-exact), hsw aliases xw region ----
  char* hbw = smem + wv * 6912;
#pragma unroll
  for (int g2 = 0; g2 < 4; g2++) {
    int e = g2 * 32 + col32;
    int ec = (e > 107) ? 107 : e;
    int row_l = ec / 18;              // 0..5
    int px = ec - row_l * 18;         // 0..17
    int ub = ((4 * wv + row_l) * 20 + px) * 4;
    uint2 l0 = *(const uint2*)&zs4[ub + oA0];
    uint2 l1 = *(const uint2*)&zs4[ub + oB0];
    uint2 l2 = *(const uint2*)&zs4[ub + oA1];
    uint2 l3 = *(const uint2*)&zs4[ub + oB1];
    uint2 l4 = *(const uint2*)&zs4[ub + oA2];
    U4 Bz0, Bz1, Bz2;
    Bz0.u4 = make_uint4(l0.x, l0.y, l1.x, l1.y);
    Bz1.u4 = make_uint4(l2.x, l2.y, l3.x, l3.y);
    Bz2.u4 = make_uint4(l4.x, l4.y, 0u, 0u);
    f32x16 a = __builtin_amdgcn_mfma_f32_32x32x16_bf16(W0.s8, Bz0.s8, tc16, 0, 0, 0);
    a = __builtin_amdgcn_mfma_f32_32x32x16_bf16(W1f.s8, Bz1.s8, a, 0, 0, 0);
    a = __builtin_amdgcn_mfma_f32_32x32x16_bf16(W2f.s8, Bz2.s8, a, 0, 0, 0);
    if (e < 108) {
      unsigned wpk[8];
#pragma unroll
      for (int m = 0; m < 8; m++)
        wpk[m] = pk_bf16(fmaxf(a[2 * m], 0.0f), fmaxf(a[2 * m + 1], 0.0f));
      int wb = row_l * 1152 + px * 64 + ((32 * h) ^ ((px & 2) << 4));
      *(uint4*)(hbw + wb)      = make_uint4(wpk[0], wpk[1], wpk[2], wpk[3]);
      *(uint4*)(hbw + wb + 16) = make_uint4(wpk[4], wpk[5], wpk[6], wpk[7]);
    }
  }
  // NO barrier: conv2 reads only this wave's strip (same-wave lgkmcnt).

  // hoist all 9 conv2 B-frags
  U4 Bt[3][3];
  {
    const unsigned short* wbase = w2c + col * 32 + q * 8;
#pragma unroll
    for (int dy = 0; dy < 3; dy++)
#pragma unroll
      for (int dx = 0; dx < 3; dx++)
        Bt[dy][dx].u4 = *(const uint4*)(wbase + (dy * 3 + dx) * 512);
  }

  // ---- conv2, loop-rotated: 18 A-reads, 36 accumulating MFMAs ----
  const f32x4 bcv = {b2v, b2v, b2v, b2v};
  f32x4 dacc[4];
#pragma unroll
  for (int i = 0; i < 4; i++) dacc[i] = bcv;
  {
    const char* hb = smem + wv * 6912;
#pragma unroll
    for (int dx = 0; dx < 3; dx++) {
      int px = col + dx;                         // 0..17
      const char* bp = hb + px * 64 + ((q * 16) ^ ((px & 2) << 4));
#pragma unroll
      for (int rr = 0; rr < 6; rr++) {
        U4 A;
        A.u4 = *(const uint4*)(bp + rr * 1152);  // one b128, imm offset
        if (rr < 4)
          dacc[rr] = __builtin_amdgcn_mfma_f32_16x16x32_bf16(A.s8, Bt[0][dx].s8, dacc[rr], 0, 0, 0);
        if (rr >= 1 && rr < 5)
          dacc[rr - 1] = __builtin_amdgcn_mfma_f32_16x16x32_bf16(A.s8, Bt[1][dx].s8, dacc[rr - 1], 0, 0, 0);
        if (rr >= 2)
          dacc[rr - 2] = __builtin_amdgcn_mfma_f32_16x16x32_bf16(A.s8, Bt[2][dx].s8, dacc[rr - 2], 0, 0, 0);
      }
    }
  }

  // ---- MSE partial (oc=col<3, ox=q*4+r, oy=wv*4+i) ----
  float s = 0.0f;
  if (col < 3) {
#pragma unroll
    for (int i = 0; i < 4; i++) {
      float4 xv = xpre[i];
      float d0 = xv.x - dacc[i][0];
      float d1 = xv.y - dacc[i][1];
      float d2 = xv.z - dacc[i][2];
      float d3 = xv.w - dacc[i][3];
      s += d0 * d0 + d1 * d1 + d2 * d2 + d3 * d3;
    }
  }
#pragma unroll
  for (int off = 32; off > 0; off >>= 1) s += __shfl_down(s, off);
  if (lane == 0) wsum[wv] = s;
  __syncthreads();   // F4
  if (tid == 0) {
    int bid = (b * 16 + by) * 16 + bx;
    partial[bid] = wsum[0] + wsum[1] + wsum[2] + wsum[3];
  }
}

// ---------------- final reduce: 8192 partials -> out[0] ----------------
__global__ __launch_bounds__(256) void reduce_kernel(const float* __restrict__ partial,
                                                     float* __restrict__ out) {
  __shared__ float wsum[4];
  int tid = threadIdx.x;
  float s = 0.0f;
#pragma unroll
  for (int i = 0; i < 8; i++) {
    float4 v = *(const float4*)&partial[(tid + 256 * i) * 4];
    s += v.x + v.y + v.z + v.w;
  }
#pragma unroll
  for (int off = 32; off > 0; off >>= 1) s += __shfl_down(s, off);
  if ((tid & 63) == 0) wsum[tid >> 6] = s;
  __syncthreads();
  if (tid == 0)
    out[0] = (wsum[0] + wsum[1] + wsum[2] + wsum[3]) * (1.0f / 6291456.0f);
}

extern "C" void kernel_launch(void* const* d_in, const int* in_sizes, int n_in,
                              void* d_out, int out_size, void* d_ws, size_t ws_size,
                              hipStream_t stream) {
  const float* x = (const float*)d_in[0];
  const int* t = (const int*)d_in[1];
  const float* W1 = (const float*)d_in[2];
  const float* b1 = (const float*)d_in[3];
  const float* tw = (const float*)d_in[4];
  const float* W2 = (const float*)d_in[5];
  const float* b2 = (const float*)d_in[6];
  const float* sched = (const float*)d_in[7];
  float* out = (float*)d_out;
  float* ws = (float*)d_ws;
  float* partial = ws + PARTIAL_OFF;

  prep_kernel<<<1, 256, 0, stream>>>(t, W1, b1, tw, W2, ws);
  dim3 grid(16, 16, BATCH);
  convloss_kernel<<<grid, 256, 0, stream>>>(x, t, sched, ws, b2, partial);
  reduce_kernel<<<1, 256, 0, stream>>>(partial, out);
}

// Round 10
// 165.189 us; speedup vs baseline: 1.0581x; 1.0581x over previous
//
#include <hip/hip_runtime.h>
#include <hip/hip_bf16.h>

#define BATCH 32
#define CH 3
#define HH 256
#define WW 256
#define KS 29
#define PAD 14
#define NT_F 1000.0f

// blur band height: 16 rows -> 1536 blocks = 6 blocks/CU (waves doubled vs
// 32-row bands), combined with R8's no-spill chunked vertical pass.
#define RB 16

typedef __attribute__((ext_vector_type(8))) short short8;
typedef __attribute__((ext_vector_type(4))) float f32x4;
typedef __attribute__((ext_vector_type(16))) float f32x16;

union U4 { short8 s8; uint4 u4; };

__device__ inline unsigned short bf16rne(float f) {
  unsigned u = __float_as_uint(f);
  unsigned r = (u + 0x7FFFu + ((u >> 16) & 1u)) >> 16;
  return (unsigned short)r;
}
__device__ inline unsigned pk_bf16(float a, float b) {
  union { __hip_bfloat162 h2; unsigned u; } cv;
  cv.h2 = __float22bfloat162_rn(make_float2(a, b));
  return cv.u;
}

// ws float layout:
//   (unused)  [1024]          @ 0
//   tcond [32][32]            @ 1024
//   w1n   ushort[3][32][16]   @ 2048
//   w2c   ushort[9][16][32]   @ 2816  (slot s holds och perm(s))
//   z     ushort[32][3][256][256] @ 5120  (bf16 blurred)
//   partial float[8192]       @ 3151872
//
// LESSONS LOG:
// R1: conv1-write bank fix correct but off critical path.
// R3: XCD swizzle cut convloss FETCH 58.5->18.5MB, dur unchanged.
// R5: private arrays need compile-time indexing (ring mod-6 -> scratch).
// R6: convloss occupancy theory falsified (+13% waves, dur worse).
// R7: barrier-removal neutral. Keep wave-private conv1 variant.
// R8: chunked no-spill blur ~43us; blur register theory dead. convloss
//     honest profile: VALU 59.4%, Mfma 27.5. Ledger 45+43+44+3 = 135.
// R9: FUSION REFUTED: per-tile blur recompute at 16x16 tiles = 3.75x
//     vertical redundancy + 9x staging redundancy at 3 blocks/CU ->
//     VALU 72%, 105us. Reverted. Remaining blur theory: waves ~95%
//     memory-stalled with only 3 waves/SIMD to hide (VALUBusy 19.8% =
//     exactly 3 waves' issue work). R4's RB=16 test of this was a
//     CORRUPT bench (components <=49 vs total 147.8, impossible).
// R10 (this): RB=16 (1536 blocks = 6/CU, LDS 18.6K, bounds(256,6)) +
//     R8's 2x8-row chunked vertical (live ~50 regs, no spill). Per-wave
//     work halved, waves/SIMD doubled. convloss/reduce/prep byte-identical
//     to R8 -> delta attributes to blur alone.
//
// NOTE (r14): do NOT fold reduce into convloss via threadfence+atomic --
// device-scope fence across 8 non-coherent XCD L2s = 6x regression.

#define PARTIAL_OFF 3151872

// ---------------- blur (+ embedded weight-prep in last block) ----------------
__global__ __launch_bounds__(256, 6) void blur_kernel(
    const float* __restrict__ x, const int* __restrict__ t,
    const float* __restrict__ sched, const float* __restrict__ W1,
    const float* __restrict__ b1, const float* __restrict__ tw,
    const float* __restrict__ W2, float* __restrict__ ws,
    unsigned short* __restrict__ z) {
  int blk = blockIdx.x;
  int tid = threadIdx.x;

  if (blk >= BATCH * CH * RB) {
    // ---- weight-prep block (runs once; convloss launches after this kernel)
    float* tcond = ws + 1024;
    unsigned short* w1n = (unsigned short*)(ws + 2048);
    unsigned short* w2c = (unsigned short*)(ws + 2816);
    for (int i = tid; i < 1536; i += 256) {          // w1n [mf][och][slot]
      int mf = i >> 9, r = i & 511;
      int och = r >> 4, s = r & 15;
      int tp = mf * 4 + (s >> 2), ci = s & 3;
      w1n[i] = (ci < 3 && tp < 9) ? bf16rne(W1[och * 27 + ci * 9 + tp])
                                  : (unsigned short)0;
    }
    for (int i = tid; i < 4608; i += 256) {          // w2c [tap][oc][slot(perm)]
      int tap = i >> 9, r = i & 511;
      int n = r >> 5, s = r & 31;
      int och = (s & 3) + 8 * ((s >> 2) & 3) + 4 * (s >> 4);   // perm(s)
      int dy = tap / 3, dx = tap - dy * 3;
      w2c[i] = (n < 3) ? bf16rne(W2[((n * 32 + och) * 3 + dy) * 3 + dx])
                       : (unsigned short)0;
    }
    for (int i = tid; i < 1024; i += 256) {          // tcond
      int b = i >> 5, o = i & 31;
      tcond[i] = b1[o] + ((float)t[b] * (1.0f / NT_F)) * tw[o];
    }
    return;
  }

  // XCD-aware bijective swizzle (1536 = 8*192): each XCD gets 12 full (b,c)
  // planes with all 16 row-bands -> halo overlap re-reads hit the local L2.
  {
    int wid = (blk & 7) * 192 + (blk >> 3);
    blk = wid;
  }

  __shared__ float vsp[RB][288];   // padded cols: idx = col + 16
  __shared__ float gkl[32];
  int rg = blk & (RB - 1);
  int bc = blk >> 4;               // log2(RB) = 4
  int b = bc / CH;
  int y0 = rg * RB;
  const float* xp = x + (size_t)bc * (HH * WW);

  // wave 0 computes this batch's gaussian kernel into LDS
  if (tid < 64) {
    float wexp = 0.0f;
    if (tid < KS) {
      float sigma = sched[t[b]];
      float xg = (float)(tid - PAD) / sigma;
      wexp = expf(-0.5f * xg * xg);
    }
    float s = wexp;
#pragma unroll
    for (int off = 32; off > 0; off >>= 1) s += __shfl_down(s, off);
    float tot = __shfl(s, 0);
    if (tid < 32) gkl[tid] = wexp / tot;
  }
  __syncthreads();

  // gaussian taps into registers once (wave-uniform broadcast reads)
  float gk[KS];
#pragma unroll
  for (int kk = 0; kk < KS; kk++) gk[kk] = gkl[kk];

  // ---- vertical pass, 2 chunks of 8 output rows (R8's proven no-spill
  // pattern): live = acc[8] + gk[29] + temps ~ 50 regs, all tap indices
  // compile-time -> no scratch at the (256,6) cap of ~85.
#pragma unroll
  for (int ch = 0; ch < 2; ch++) {
    float acc[8];
#pragma unroll
    for (int yy = 0; yy < 8; yy++) acc[yy] = 0.0f;
#pragma unroll
    for (int i = 0; i < 36; i++) {         // input rows y0+8ch-14 .. +21
      int gy = y0 + 8 * ch - PAD + i;
      gy = (gy < 0) ? -gy : gy;
      gy = (gy >= HH) ? (2 * HH - 2 - gy) : gy;
      float v = xp[gy * WW + tid];
#pragma unroll
      for (int yy = 0; yy < 8; yy++) {
        int kk = i - yy;                   // compile-time per (i,yy)
        if (kk >= 0 && kk < KS) acc[yy] += gk[kk] * v;
      }
    }
#pragma unroll
    for (int yy = 0; yy < 8; yy++) vsp[8 * ch + yy][tid + 16] = acc[yy];
  }
  __syncthreads();
  {
    // 256 threads = 16 rows x 16 cols: single-pass horizontal mirror pads
    int row = tid >> 4, i2 = tid & 15;
    vsp[row][i2] = vsp[row][32 - i2];
    vsp[row][272 + i2] = vsp[row][270 - i2];
  }
  __syncthreads();

  size_t zb = (size_t)bc * (HH * WW);
#pragma unroll
  for (int it = 0; it < RB / 4; ++it) {   // 4 its: 1024 4-px units / 256 thr
    int unit = tid + 256 * it;
    int row = unit >> 6, cg = unit & 63;
    float w[36];
#pragma unroll
    for (int i = 0; i < 9; i++)
      *(float4*)&w[4 * i] = *(const float4*)&vsp[row][4 * (cg + i)];
    float o0 = 0, o1 = 0, o2 = 0, o3 = 0;
#pragma unroll
    for (int kk = 0; kk < KS; kk++) {
      float kv = gk[kk];
      o0 += kv * w[2 + kk];
      o1 += kv * w[3 + kk];
      o2 += kv * w[4 + kk];
      o3 += kv * w[5 + kk];
    }
    unsigned u0 = pk_bf16(o0, o1);
    unsigned u1 = pk_bf16(o2, o3);
    *(uint2*)&z[zb + (size_t)(y0 + row) * WW + 4 * cg] = make_uint2(u0, u1);
  }
}

// ---------------- fused conv1+ReLU+conv2+MSE via bf16 MFMA ----------------
// R7-exact (best measured variant): single mid-kernel barrier, wave-private
// conv1 strips, no B2.
__global__ __launch_bounds__(256, 5) void convloss_kernel(
    const float* __restrict__ x, const float* __restrict__ ws,
    const float* __restrict__ b2g, float* __restrict__ partial) {
  __shared__ __align__(16) unsigned short zs4[400 * 4];      // [y*20+x][ci0..2,pad]
  __shared__ __align__(16) unsigned short hsw[4 * 6 * 18 * 32]; // per-wave strips
  __shared__ float wsum[4];

  const float* tcond = ws + 1024;
  const unsigned short* w1n = (const unsigned short*)(ws + 2048);
  const unsigned short* w2c = (const unsigned short*)(ws + 2816);
  const unsigned short* zg = (const unsigned short*)(ws + 5120);

  // XCD-aware bijective swizzle (8192 = 8*1024)
  int flat = (blockIdx.z * 16 + blockIdx.y) * 16 + blockIdx.x;
  int wid = (flat & 7) * 1024 + (flat >> 3);
  int b = wid >> 8;
  int by = (wid >> 4) & 15;
  int bx = wid & 15;

  int tid = threadIdx.x;
  int x0 = bx * 16, y0 = by * 16;
  const unsigned short* zbp = zg + (size_t)b * 3 * HH * WW;

  int lane = tid & 63;
  int q = lane >> 4;        // quad (16x16 shapes)
  int col = lane & 15;      // 16x16 m/n index
  int col32 = lane & 31;    // 32x32 n index (pixel)
  int h = lane >> 5;        // 32x32 half
  int wv = tid >> 6;        // wave id

  // ---- vectorized z staging: 200 threads, 2-px units, b32 loads ----
  if (tid < 200) {
    int zy = tid / 10;
    int zx2 = tid - zy * 10;
    int gy = y0 - 2 + zy;
    int gx0 = x0 - 2 + 2 * zx2;
    bool ok = ((unsigned)gy < (unsigned)HH) && ((unsigned)gx0 < (unsigned)(WW - 1));
    int cy = (gy < 0) ? 0 : ((gy > 255) ? 255 : gy);
    int cx = (gx0 < 0) ? 0 : ((gx0 > 254) ? 254 : gx0);
    int gi = cy * WW + cx;
    unsigned c0 = *(const unsigned*)&zbp[gi];
    unsigned c1 = *(const unsigned*)&zbp[HH * WW + gi];
    unsigned c2 = *(const unsigned*)&zbp[2 * HH * WW + gi];
    unsigned m = ok ? 0xFFFFFFFFu : 0u;
    c0 &= m; c1 &= m; c2 &= m;
    uint4 o;
    o.x = (c0 & 0xFFFFu) | (c1 << 16);        // px0: ci0,ci1
    o.y = c2 & 0xFFFFu;                       // px0: ci2,pad
    o.z = (c0 >> 16) | (c1 & 0xFFFF0000u);    // px1: ci0,ci1
    o.w = c2 >> 16;                           // px1: ci2,pad
    *(uint4*)&zs4[(zy * 20 + 2 * zx2) * 4] = o;
  }

  // conv1 A fragments = weights [m=och][k=slot(h*8+j)]: b128 each
  U4 W0, W1f, W2f;
  W0.u4  = *(const uint4*)(w1n + 0 * 512 + col32 * 16 + h * 8);
  W1f.u4 = *(const uint4*)(w1n + 1 * 512 + col32 * 16 + h * 8);
  W2f.u4 = *(const uint4*)(w1n + 2 * 512 + col32 * 16 + h * 8);

  // conv1 C-init: tcond bias per (reg,h): och = (reg&3) + 8*(reg>>2) + 4h
  f32x16 tc16;
#pragma unroll
  for (int r1 = 0; r1 < 4; r1++) {
    float4 v = *(const float4*)(tcond + b * 32 + 4 * h + 8 * r1);
    tc16[4 * r1 + 0] = v.x;
    tc16[4 * r1 + 1] = v.y;
    tc16[4 * r1 + 2] = v.z;
    tc16[4 * r1 + 3] = v.w;
  }

  int colc = (col < 3) ? col : 0;
  float b2v = b2g[colc];

  // MSE x prefetch HOISTED above B1 (cold HBM stream; consumed at the end)
  const float* xb = x + (size_t)b * 3 * HH * WW;
  float4 xpre[4];
#pragma unroll
  for (int i = 0; i < 4; i++) {
    int g2 = wv * 4 + i;
    xpre[i] = *(const float4*)&xb[colc * (HH * WW) + (y0 + g2) * WW + x0 + q * 4];
  }

  __syncthreads();   // B1: z staged (ONLY mid-kernel barrier)

  // per-lane b64 read offsets (ushort units) for the 3 MFMAs' tap pairs
  int oA0 = h ? 8 : 0, oB0 = h ? 80 : 4;
  int oA1 = h ? 160 : 84, oB1 = h ? 164 : 88;
  const int oA2 = 168;

  // ---- P1: wave-private conv1 -> own h strip (rows 4wv..4wv+5, 18 px) ----
  char* hbw = (char*)hsw + wv * 6912;
#pragma unroll
  for (int g2 = 0; g2 < 4; g2++) {
    int e = g2 * 32 + col32;
    int ec = (e > 107) ? 107 : e;
    int row_l = ec / 18;              // 0..5
    int px = ec - row_l * 18;         // 0..17
    int ub = ((4 * wv + row_l) * 20 + px) * 4;
    uint2 l0 = *(const uint2*)&zs4[ub + oA0];
    uint2 l1 = *(const uint2*)&zs4[ub + oB0];
    uint2 l2 = *(const uint2*)&zs4[ub + oA1];
    uint2 l3 = *(const uint2*)&zs4[ub + oB1];
    uint2 l4 = *(const uint2*)&zs4[ub + oA2];
    U4 Bz0, Bz1, Bz2;
    Bz0.u4 = make_uint4(l0.x, l0.y, l1.x, l1.y);
    Bz1.u4 = make_uint4(l2.x, l2.y, l3.x, l3.y);
    Bz2.u4 = make_uint4(l4.x, l4.y, 0u, 0u);
    f32x16 a = __builtin_amdgcn_mfma_f32_32x32x16_bf16(W0.s8, Bz0.s8, tc16, 0, 0, 0);
    a = __builtin_amdgcn_mfma_f32_32x32x16_bf16(W1f.s8, Bz1.s8, a, 0, 0, 0);
    a = __builtin_amdgcn_mfma_f32_32x32x16_bf16(W2f.s8, Bz2.s8, a, 0, 0, 0);
    if (e < 108) {
      unsigned wpk[8];
#pragma unroll
      for (int m = 0; m < 8; m++)
        wpk[m] = pk_bf16(fmaxf(a[2 * m], 0.0f), fmaxf(a[2 * m + 1], 0.0f));
      int wb = row_l * 1152 + px * 64 + ((32 * h) ^ ((px & 2) << 4));
      *(uint4*)(hbw + wb)      = make_uint4(wpk[0], wpk[1], wpk[2], wpk[3]);
      *(uint4*)(hbw + wb + 16) = make_uint4(wpk[4], wpk[5], wpk[6], wpk[7]);
    }
  }
  // NO barrier: conv2 reads only this wave's strip (same-wave lgkmcnt).

  // hoist all 9 conv2 B-frags
  U4 Bt[3][3];
  {
    const unsigned short* wbase = w2c + col * 32 + q * 8;
#pragma unroll
    for (int dy = 0; dy < 3; dy++)
#pragma unroll
      for (int dx = 0; dx < 3; dx++)
        Bt[dy][dx].u4 = *(const uint4*)(wbase + (dy * 3 + dx) * 512);
  }

  // ---- conv2, loop-rotated: 18 A-reads, 36 accumulating MFMAs ----
  const f32x4 bcv = {b2v, b2v, b2v, b2v};
  f32x4 dacc[4];
#pragma unroll
  for (int i = 0; i < 4; i++) dacc[i] = bcv;
  {
    const char* hb = (const char*)hsw + wv * 6912;
#pragma unroll
    for (int dx = 0; dx < 3; dx++) {
      int px = col + dx;                         // 0..17
      const char* bp = hb + px * 64 + ((q * 16) ^ ((px & 2) << 4));
#pragma unroll
      for (int rr = 0; rr < 6; rr++) {
        U4 A;
        A.u4 = *(const uint4*)(bp + rr * 1152);  // one b128, imm offset
        if (rr < 4)
          dacc[rr] = __builtin_amdgcn_mfma_f32_16x16x32_bf16(A.s8, Bt[0][dx].s8, dacc[rr], 0, 0, 0);
        if (rr >= 1 && rr < 5)
          dacc[rr - 1] = __builtin_amdgcn_mfma_f32_16x16x32_bf16(A.s8, Bt[1][dx].s8, dacc[rr - 1], 0, 0, 0);
        if (rr >= 2)
          dacc[rr - 2] = __builtin_amdgcn_mfma_f32_16x16x32_bf16(A.s8, Bt[2][dx].s8, dacc[rr - 2], 0, 0, 0);
      }
    }
  }

  // ---- MSE partial (oc=col<3, ox=q*4+r, oy=wv*4+i) ----
  float s = 0.0f;
  if (col < 3) {
#pragma unroll
    for (int i = 0; i < 4; i++) {
      float4 xv = xpre[i];
      float d0 = xv.x - dacc[i][0];
      float d1 = xv.y - dacc[i][1];
      float d2 = xv.z - dacc[i][2];
      float d3 = xv.w - dacc[i][3];
      s += d0 * d0 + d1 * d1 + d2 * d2 + d3 * d3;
    }
  }
#pragma unroll
  for (int off = 32; off > 0; off >>= 1) s += __shfl_down(s, off);
  if (lane == 0) wsum[wv] = s;
  __syncthreads();   // B3
  if (tid == 0) {
    int bid = (b * 16 + by) * 16 + bx;
    partial[bid] = wsum[0] + wsum[1] + wsum[2] + wsum[3];
  }
}

// ---------------- final reduce: 8192 partials -> out[0] ----------------
__global__ __launch_bounds__(256) void reduce_kernel(const float* __restrict__ partial,
                                                     float* __restrict__ out) {
  __shared__ float wsum[4];
  int tid = threadIdx.x;
  float s = 0.0f;
#pragma unroll
  for (int i = 0; i < 8; i++) {
    float4 v = *(const float4*)&partial[(tid + 256 * i) * 4];
    s += v.x + v.y + v.z + v.w;
  }
#pragma unroll
  for (int off = 32; off > 0; off >>= 1) s += __shfl_down(s, off);
  if ((tid & 63) == 0) wsum[tid >> 6] = s;
  __syncthreads();
  if (tid == 0)
    out[0] = (wsum[0] + wsum[1] + wsum[2] + wsum[3]) * (1.0f / 6291456.0f);
}

extern "C" void kernel_launch(void* const* d_in, const int* in_sizes, int n_in,
                              void* d_out, int out_size, void* d_ws, size_t ws_size,
                              hipStream_t stream) {
  const float* x = (const float*)d_in[0];
  const int* t = (const int*)d_in[1];
  const float* W1 = (const float*)d_in[2];
  const float* b1 = (const float*)d_in[3];
  const float* tw = (const float*)d_in[4];
  const float* W2 = (const float*)d_in[5];
  const float* b2 = (const float*)d_in[6];
  const float* sched = (const float*)d_in[7];
  float* out = (float*)d_out;
  float* ws = (float*)d_ws;
  unsigned short* z = (unsigned short*)(ws + 5120);
  float* partial = ws + PARTIAL_OFF;

  blur_kernel<<<BATCH * CH * RB + 1, 256, 0, stream>>>(x, t, sched, W1, b1, tw, W2, ws, z);
  dim3 grid(16, 16, BATCH);
  convloss_kernel<<<grid, 256, 0, stream>>>(x, ws, b2, partial);
  reduce_kernel<<<1, 256, 0, stream>>>(partial, out);
}

// Round 11
// 134.064 us; speedup vs baseline: 1.3038x; 1.2322x over previous
//
#include <hip/hip_runtime.h>
#include <hip/hip_bf16.h>

#define BATCH 32
#define CH 3
#define HH 256
#define WW 256
#define KS 29
#define PAD 14
#define NT_F 1000.0f

// blur band height: 16 rows -> 1536 blocks; with bounds(256,4) the reg cap is
// 128 (no spill at ~80 live) and occupancy = 4 blocks/CU (16 waves/CU band).
#define RB 16

typedef __attribute__((ext_vector_type(8))) short short8;
typedef __attribute__((ext_vector_type(4))) float f32x4;
typedef __attribute__((ext_vector_type(16))) float f32x16;

union U4 { short8 s8; uint4 u4; };

__device__ inline unsigned short bf16rne(float f) {
  unsigned u = __float_as_uint(f);
  unsigned r = (u + 0x7FFFu + ((u >> 16) & 1u)) >> 16;
  return (unsigned short)r;
}
__device__ inline unsigned pk_bf16(float a, float b) {
  union { __hip_bfloat162 h2; unsigned u; } cv;
  cv.h2 = __float22bfloat162_rn(make_float2(a, b));
  return cv.u;
}

// ws float layout:
//   (unused)  [1024]          @ 0
//   tcond [32][32]            @ 1024
//   w1n   ushort[3][32][16]   @ 2048
//   w2c   ushort[9][16][32]   @ 2816  (slot s holds och perm(s))
//   z     ushort[32][3][256][256] @ 5120  (bf16 blurred)
//   partial float[8192]       @ 3151872
//
// LESSONS LOG:
// R1: conv1-write bank fix correct but off critical path.
// R3: XCD swizzle cut convloss FETCH 58.5->18.5MB, dur unchanged.
// R5: private arrays need compile-time indexing (ring mod-6 -> scratch).
// R6: convloss occupancy theory falsified (+13% waves, dur worse).
// R7: barrier-removal neutral. Keep wave-private conv1 variant.
// R8: chunked no-spill blur ~43us (bounds(256,3), VGPR 80, WRITE==z).
// R9: fusion refuted (3.75x blur redundancy at 16x16 tiles -> 105us).
// R10: LAUNCH_BOUNDS SPILL RULE found: bounds(256,6) caps VGPR at the
//     64-reg occupancy quantum -> gk[29]+acc spill to scratch (VGPR=40,
//     WRITE 76.8MB vs z's 12.6, 53us). Same signature in R5. Wave-count
//     theory was never tested at a healthy reg budget.
// R11 (this): the untested middle point: bounds(256,4) = 128-reg cap.
//     R8's 80-reg allocation fits (no spill) AND lands in the 16-waves/CU
//     band = 4 blocks/CU = 4 waves/SIMD (vs R3's grid-limited 3), with
//     RB=16's halved per-block path. convloss/reduce byte-identical.
//
// NOTE (r14): do NOT fold reduce into convloss via threadfence+atomic --
// device-scope fence across 8 non-coherent XCD L2s = 6x regression.

#define PARTIAL_OFF 3151872

// ---------------- blur (+ embedded weight-prep in last block) ----------------
__global__ __launch_bounds__(256, 4) void blur_kernel(
    const float* __restrict__ x, const int* __restrict__ t,
    const float* __restrict__ sched, const float* __restrict__ W1,
    const float* __restrict__ b1, const float* __restrict__ tw,
    const float* __restrict__ W2, float* __restrict__ ws,
    unsigned short* __restrict__ z) {
  int blk = blockIdx.x;
  int tid = threadIdx.x;

  if (blk >= BATCH * CH * RB) {
    // ---- weight-prep block (runs once; convloss launches after this kernel)
    float* tcond = ws + 1024;
    unsigned short* w1n = (unsigned short*)(ws + 2048);
    unsigned short* w2c = (unsigned short*)(ws + 2816);
    for (int i = tid; i < 1536; i += 256) {          // w1n [mf][och][slot]
      int mf = i >> 9, r = i & 511;
      int och = r >> 4, s = r & 15;
      int tp = mf * 4 + (s >> 2), ci = s & 3;
      w1n[i] = (ci < 3 && tp < 9) ? bf16rne(W1[och * 27 + ci * 9 + tp])
                                  : (unsigned short)0;
    }
    for (int i = tid; i < 4608; i += 256) {          // w2c [tap][oc][slot(perm)]
      int tap = i >> 9, r = i & 511;
      int n = r >> 5, s = r & 31;
      int och = (s & 3) + 8 * ((s >> 2) & 3) + 4 * (s >> 4);   // perm(s)
      int dy = tap / 3, dx = tap - dy * 3;
      w2c[i] = (n < 3) ? bf16rne(W2[((n * 32 + och) * 3 + dy) * 3 + dx])
                       : (unsigned short)0;
    }
    for (int i = tid; i < 1024; i += 256) {          // tcond
      int b = i >> 5, o = i & 31;
      tcond[i] = b1[o] + ((float)t[b] * (1.0f / NT_F)) * tw[o];
    }
    return;
  }

  // XCD-aware bijective swizzle (1536 = 8*192): each XCD gets 12 full (b,c)
  // planes with all 16 row-bands -> halo overlap re-reads hit the local L2.
  {
    int wid = (blk & 7) * 192 + (blk >> 3);
    blk = wid;
  }

  __shared__ float vsp[RB][288];   // padded cols: idx = col + 16
  __shared__ float gkl[32];
  int rg = blk & (RB - 1);
  int bc = blk >> 4;               // log2(RB) = 4
  int b = bc / CH;
  int y0 = rg * RB;
  const float* xp = x + (size_t)bc * (HH * WW);

  // wave 0 computes this batch's gaussian kernel into LDS
  if (tid < 64) {
    float wexp = 0.0f;
    if (tid < KS) {
      float sigma = sched[t[b]];
      float xg = (float)(tid - PAD) / sigma;
      wexp = expf(-0.5f * xg * xg);
    }
    float s = wexp;
#pragma unroll
    for (int off = 32; off > 0; off >>= 1) s += __shfl_down(s, off);
    float tot = __shfl(s, 0);
    if (tid < 32) gkl[tid] = wexp / tot;
  }
  __syncthreads();

  // gaussian taps into registers once (wave-uniform broadcast reads)
  float gk[KS];
#pragma unroll
  for (int kk = 0; kk < KS; kk++) gk[kk] = gkl[kk];

  // ---- vertical pass, 2 chunks of 8 output rows (R8's proven no-spill
  // pattern): live = acc[8] + gk[29] + temps ~ 50-80 regs, all tap indices
  // compile-time -> fits the 128-reg cap of bounds(256,4) with slack.
#pragma unroll
  for (int ch = 0; ch < 2; ch++) {
    float acc[8];
#pragma unroll
    for (int yy = 0; yy < 8; yy++) acc[yy] = 0.0f;
#pragma unroll
    for (int i = 0; i < 36; i++) {         // input rows y0+8ch-14 .. +21
      int gy = y0 + 8 * ch - PAD + i;
      gy = (gy < 0) ? -gy : gy;
      gy = (gy >= HH) ? (2 * HH - 2 - gy) : gy;
      float v = xp[gy * WW + tid];
#pragma unroll
      for (int yy = 0; yy < 8; yy++) {
        int kk = i - yy;                   // compile-time per (i,yy)
        if (kk >= 0 && kk < KS) acc[yy] += gk[kk] * v;
      }
    }
#pragma unroll
    for (int yy = 0; yy < 8; yy++) vsp[8 * ch + yy][tid + 16] = acc[yy];
  }
  __syncthreads();
  {
    // 256 threads = 16 rows x 16 cols: single-pass horizontal mirror pads
    int row = tid >> 4, i2 = tid & 15;
    vsp[row][i2] = vsp[row][32 - i2];
    vsp[row][272 + i2] = vsp[row][270 - i2];
  }
  __syncthreads();

  size_t zb = (size_t)bc * (HH * WW);
#pragma unroll
  for (int it = 0; it < RB / 4; ++it) {   // 4 its: 1024 4-px units / 256 thr
    int unit = tid + 256 * it;
    int row = unit >> 6, cg = unit & 63;
    float w[36];
#pragma unroll
    for (int i = 0; i < 9; i++)
      *(float4*)&w[4 * i] = *(const float4*)&vsp[row][4 * (cg + i)];
    float o0 = 0, o1 = 0, o2 = 0, o3 = 0;
#pragma unroll
    for (int kk = 0; kk < KS; kk++) {
      float kv = gk[kk];
      o0 += kv * w[2 + kk];
      o1 += kv * w[3 + kk];
      o2 += kv * w[4 + kk];
      o3 += kv * w[5 + kk];
    }
    unsigned u0 = pk_bf16(o0, o1);
    unsigned u1 = pk_bf16(o2, o3);
    *(uint2*)&z[zb + (size_t)(y0 + row) * WW + 4 * cg] = make_uint2(u0, u1);
  }
}

// ---------------- fused conv1+ReLU+conv2+MSE via bf16 MFMA ----------------
// R7-exact (best measured variant): single mid-kernel barrier, wave-private
// conv1 strips, no B2.
__global__ __launch_bounds__(256, 5) void convloss_kernel(
    const float* __restrict__ x, const float* __restrict__ ws,
    const float* __restrict__ b2g, float* __restrict__ partial) {
  __shared__ __align__(16) unsigned short zs4[400 * 4];      // [y*20+x][ci0..2,pad]
  __shared__ __align__(16) unsigned short hsw[4 * 6 * 18 * 32]; // per-wave strips
  __shared__ float wsum[4];

  const float* tcond = ws + 1024;
  const unsigned short* w1n = (const unsigned short*)(ws + 2048);
  const unsigned short* w2c = (const unsigned short*)(ws + 2816);
  const unsigned short* zg = (const unsigned short*)(ws + 5120);

  // XCD-aware bijective swizzle (8192 = 8*1024)
  int flat = (blockIdx.z * 16 + blockIdx.y) * 16 + blockIdx.x;
  int wid = (flat & 7) * 1024 + (flat >> 3);
  int b = wid >> 8;
  int by = (wid >> 4) & 15;
  int bx = wid & 15;

  int tid = threadIdx.x;
  int x0 = bx * 16, y0 = by * 16;
  const unsigned short* zbp = zg + (size_t)b * 3 * HH * WW;

  int lane = tid & 63;
  int q = lane >> 4;        // quad (16x16 shapes)
  int col = lane & 15;      // 16x16 m/n index
  int col32 = lane & 31;    // 32x32 n index (pixel)
  int h = lane >> 5;        // 32x32 half
  int wv = tid >> 6;        // wave id

  // ---- vectorized z staging: 200 threads, 2-px units, b32 loads ----
  if (tid < 200) {
    int zy = tid / 10;
    int zx2 = tid - zy * 10;
    int gy = y0 - 2 + zy;
    int gx0 = x0 - 2 + 2 * zx2;
    bool ok = ((unsigned)gy < (unsigned)HH) && ((unsigned)gx0 < (unsigned)(WW - 1));
    int cy = (gy < 0) ? 0 : ((gy > 255) ? 255 : gy);
    int cx = (gx0 < 0) ? 0 : ((gx0 > 254) ? 254 : gx0);
    int gi = cy * WW + cx;
    unsigned c0 = *(const unsigned*)&zbp[gi];
    unsigned c1 = *(const unsigned*)&zbp[HH * WW + gi];
    unsigned c2 = *(const unsigned*)&zbp[2 * HH * WW + gi];
    unsigned m = ok ? 0xFFFFFFFFu : 0u;
    c0 &= m; c1 &= m; c2 &= m;
    uint4 o;
    o.x = (c0 & 0xFFFFu) | (c1 << 16);        // px0: ci0,ci1
    o.y = c2 & 0xFFFFu;                       // px0: ci2,pad
    o.z = (c0 >> 16) | (c1 & 0xFFFF0000u);    // px1: ci0,ci1
    o.w = c2 >> 16;                           // px1: ci2,pad
    *(uint4*)&zs4[(zy * 20 + 2 * zx2) * 4] = o;
  }

  // conv1 A fragments = weights [m=och][k=slot(h*8+j)]: b128 each
  U4 W0, W1f, W2f;
  W0.u4  = *(const uint4*)(w1n + 0 * 512 + col32 * 16 + h * 8);
  W1f.u4 = *(const uint4*)(w1n + 1 * 512 + col32 * 16 + h * 8);
  W2f.u4 = *(const uint4*)(w1n + 2 * 512 + col32 * 16 + h * 8);

  // conv1 C-init: tcond bias per (reg,h): och = (reg&3) + 8*(reg>>2) + 4h
  f32x16 tc16;
#pragma unroll
  for (int r1 = 0; r1 < 4; r1++) {
    float4 v = *(const float4*)(tcond + b * 32 + 4 * h + 8 * r1);
    tc16[4 * r1 + 0] = v.x;
    tc16[4 * r1 + 1] = v.y;
    tc16[4 * r1 + 2] = v.z;
    tc16[4 * r1 + 3] = v.w;
  }

  int colc = (col < 3) ? col : 0;
  float b2v = b2g[colc];

  // MSE x prefetch HOISTED above B1 (cold HBM stream; consumed at the end)
  const float* xb = x + (size_t)b * 3 * HH * WW;
  float4 xpre[4];
#pragma unroll
  for (int i = 0; i < 4; i++) {
    int g2 = wv * 4 + i;
    xpre[i] = *(const float4*)&xb[colc * (HH * WW) + (y0 + g2) * WW + x0 + q * 4];
  }

  __syncthreads();   // B1: z staged (ONLY mid-kernel barrier)

  // per-lane b64 read offsets (ushort units) for the 3 MFMAs' tap pairs
  int oA0 = h ? 8 : 0, oB0 = h ? 80 : 4;
  int oA1 = h ? 160 : 84, oB1 = h ? 164 : 88;
  const int oA2 = 168;

  // ---- P1: wave-private conv1 -> own h strip (rows 4wv..4wv+5, 18 px) ----
  char* hbw = (char*)hsw + wv * 6912;
#pragma unroll
  for (int g2 = 0; g2 < 4; g2++) {
    int e = g2 * 32 + col32;
    int ec = (e > 107) ? 107 : e;
    int row_l = ec / 18;              // 0..5
    int px = ec - row_l * 18;         // 0..17
    int ub = ((4 * wv + row_l) * 20 + px) * 4;
    uint2 l0 = *(const uint2*)&zs4[ub + oA0];
    uint2 l1 = *(const uint2*)&zs4[ub + oB0];
    uint2 l2 = *(const uint2*)&zs4[ub + oA1];
    uint2 l3 = *(const uint2*)&zs4[ub + oB1];
    uint2 l4 = *(const uint2*)&zs4[ub + oA2];
    U4 Bz0, Bz1, Bz2;
    Bz0.u4 = make_uint4(l0.x, l0.y, l1.x, l1.y);
    Bz1.u4 = make_uint4(l2.x, l2.y, l3.x, l3.y);
    Bz2.u4 = make_uint4(l4.x, l4.y, 0u, 0u);
    f32x16 a = __builtin_amdgcn_mfma_f32_32x32x16_bf16(W0.s8, Bz0.s8, tc16, 0, 0, 0);
    a = __builtin_amdgcn_mfma_f32_32x32x16_bf16(W1f.s8, Bz1.s8, a, 0, 0, 0);
    a = __builtin_amdgcn_mfma_f32_32x32x16_bf16(W2f.s8, Bz2.s8, a, 0, 0, 0);
    if (e < 108) {
      unsigned wpk[8];
#pragma unroll
      for (int m = 0; m < 8; m++)
        wpk[m] = pk_bf16(fmaxf(a[2 * m], 0.0f), fmaxf(a[2 * m + 1], 0.0f));
      int wb = row_l * 1152 + px * 64 + ((32 * h) ^ ((px & 2) << 4));
      *(uint4*)(hbw + wb)      = make_uint4(wpk[0], wpk[1], wpk[2], wpk[3]);
      *(uint4*)(hbw + wb + 16) = make_uint4(wpk[4], wpk[5], wpk[6], wpk[7]);
    }
  }
  // NO barrier: conv2 reads only this wave's strip (same-wave lgkmcnt).

  // hoist all 9 conv2 B-frags
  U4 Bt[3][3];
  {
    const unsigned short* wbase = w2c + col * 32 + q * 8;
#pragma unroll
    for (int dy = 0; dy < 3; dy++)
#pragma unroll
      for (int dx = 0; dx < 3; dx++)
        Bt[dy][dx].u4 = *(const uint4*)(wbase + (dy * 3 + dx) * 512);
  }

  // ---- conv2, loop-rotated: 18 A-reads, 36 accumulating MFMAs ----
  const f32x4 bcv = {b2v, b2v, b2v, b2v};
  f32x4 dacc[4];
#pragma unroll
  for (int i = 0; i < 4; i++) dacc[i] = bcv;
  {
    const char* hb = (const char*)hsw + wv * 6912;
#pragma unroll
    for (int dx = 0; dx < 3; dx++) {
      int px = col + dx;                         // 0..17
      const char* bp = hb + px * 64 + ((q * 16) ^ ((px & 2) << 4));
#pragma unroll
      for (int rr = 0; rr < 6; rr++) {
        U4 A;
        A.u4 = *(const uint4*)(bp + rr * 1152);  // one b128, imm offset
        if (rr < 4)
          dacc[rr] = __builtin_amdgcn_mfma_f32_16x16x32_bf16(A.s8, Bt[0][dx].s8, dacc[rr], 0, 0, 0);
        if (rr >= 1 && rr < 5)
          dacc[rr - 1] = __builtin_amdgcn_mfma_f32_16x16x32_bf16(A.s8, Bt[1][dx].s8, dacc[rr - 1], 0, 0, 0);
        if (rr >= 2)
          dacc[rr - 2] = __builtin_amdgcn_mfma_f32_16x16x32_bf16(A.s8, Bt[2][dx].s8, dacc[rr - 2], 0, 0, 0);
      }
    }
  }

  // ---- MSE partial (oc=col<3, ox=q*4+r, oy=wv*4+i) ----
  float s = 0.0f;
  if (col < 3) {
#pragma unroll
    for (int i = 0; i < 4; i++) {
      float4 xv = xpre[i];
      float d0 = xv.x - dacc[i][0];
      float d1 = xv.y - dacc[i][1];
      float d2 = xv.z - dacc[i][2];
      float d3 = xv.w - dacc[i][3];
      s += d0 * d0 + d1 * d1 + d2 * d2 + d3 * d3;
    }
  }
#pragma unroll
  for (int off = 32; off > 0; off >>= 1) s += __shfl_down(s, off);
  if (lane == 0) wsum[wv] = s;
  __syncthreads();   // B3
  if (tid == 0) {
    int bid = (b * 16 + by) * 16 + bx;
    partial[bid] = wsum[0] + wsum[1] + wsum[2] + wsum[3];
  }
}

// ---------------- final reduce: 8192 partials -> out[0] ----------------
__global__ __launch_bounds__(256) void reduce_kernel(const float* __restrict__ partial,
                                                     float* __restrict__ out) {
  __shared__ float wsum[4];
  int tid = threadIdx.x;
  float s = 0.0f;
#pragma unroll
  for (int i = 0; i < 8; i++) {
    float4 v = *(const float4*)&partial[(tid + 256 * i) * 4];
    s += v.x + v.y + v.z + v.w;
  }
#pragma unroll
  for (int off = 32; off > 0; off >>= 1) s += __shfl_down(s, off);
  if ((tid & 63) == 0) wsum[tid >> 6] = s;
  __syncthreads();
  if (tid == 0)
    out[0] = (wsum[0] + wsum[1] + wsum[2] + wsum[3]) * (1.0f / 6291456.0f);
}

extern "C" void kernel_launch(void* const* d_in, const int* in_sizes, int n_in,
                              void* d_out, int out_size, void* d_ws, size_t ws_size,
                              hipStream_t stream) {
  const float* x = (const float*)d_in[0];
  const int* t = (const int*)d_in[1];
  const float* W1 = (const float*)d_in[2];
  const float* b1 = (const float*)d_in[3];
  const float* tw = (const float*)d_in[4];
  const float* W2 = (const float*)d_in[5];
  const float* b2 = (const float*)d_in[6];
  const float* sched = (const float*)d_in[7];
  float* out = (float*)d_out;
  float* ws = (float*)d_ws;
  unsigned short* z = (unsigned short*)(ws + 5120);
  float* partial = ws + PARTIAL_OFF;

  blur_kernel<<<BATCH * CH * RB + 1, 256, 0, stream>>>(x, t, sched, W1, b1, tw, W2, ws, z);
  dim3 grid(16, 16, BATCH);
  convloss_kernel<<<grid, 256, 0, stream>>>(x, ws, b2, partial);
  reduce_kernel<<<1, 256, 0, stream>>>(partial, out);
}